// Round 4
// baseline (853.854 us; speedup 1.0000x reference)
//
#include <hip/hip_runtime.h>
#include <hip/hip_fp16.h>

// NNConv particle GNN, round 4:
//  - BN1 edge stats via exact second-moment closed form (M = ea^T ea)
//  - h2 staged fp16 in SRC-SORTED order (scatter on write, coalesced read)
//  - combo[slot] = posD | nl<<27 (no perm gather, no divergent search)
//  - k0 folded into k5_gemm (xb) and aggregator (root term)
//  - own-BN1 stats fused into aggregator
// BN training mode => linear biases b1/b2/own_b1/own_b2 cancel exactly.

#define N_NODES 50000
#define N_EDGES 800000
#define SD 32
#define OC 16
#define HID 32
#define BN_EPS 1e-5f
#define ETILES 3125   // 800000/256
#define NTILES 196    // ceil(50000/256)

// ---- workspace byte offsets (64B-aligned), total 87,605,504 B ----
#define OFF_STATS 0u          // 256 f
#define OFF_M     1024u       // 1024 f
#define OFF_EASUM 5120u       // 32 f
#define OFF_DEGS  5376u       // 50000 i
#define OFF_CURS  205376u
#define OFF_DEGD  405376u
#define OFF_CURD  605376u     // memset [0, 805376)
#define OFF_BASES 805376u     // 50001 i
#define OFF_BASED 1005440u    // 50001 i
#define OFF_POSS  1205504u    // 800000 i
#define OFF_COMBO 4405504u    // 800000 u
#define OFF_AGG   7605504u    // 800000 f
#define OFF_H2S   10805504u   // 25.6M half
#define OFF_MSGB  62005504u   // 12.8M half

__device__ __forceinline__ float f4get(const float4& v, int ii) {
  return ii == 0 ? v.x : ii == 1 ? v.y : ii == 2 ? v.z : v.w;
}

__device__ __forceinline__ unsigned pack2(float a, float b) {
  __half2 h = __floats2half2_rn(a, b);
  return *reinterpret_cast<unsigned*>(&h);
}
__device__ __forceinline__ void unpk8(uint4 u, float* o) {
  __half2 a = *reinterpret_cast<__half2*>(&u.x), b = *reinterpret_cast<__half2*>(&u.y);
  __half2 c = *reinterpret_cast<__half2*>(&u.z), d = *reinterpret_cast<__half2*>(&u.w);
  float2 fa = __half22float2(a), fb = __half22float2(b);
  float2 fc = __half22float2(c), fd = __half22float2(d);
  o[0] = fa.x; o[1] = fa.y; o[2] = fb.x; o[3] = fb.y;
  o[4] = fc.x; o[5] = fc.y; o[6] = fd.x; o[7] = fd.y;
}

template<int I4, int IOFF>
__device__ __forceinline__ void mv_acc(const float4* __restrict__ rp,
                                       const float* __restrict__ wlds,
                                       float z[HID]) {
#pragma unroll
  for (int i4 = 0; i4 < I4; ++i4) {
    float4 rv = rp[i4];
#pragma unroll
    for (int ii = 0; ii < 4; ++ii) {
      float s = f4get(rv, ii);
      const float* wrow = wlds + (IOFF + i4 * 4 + ii) * HID;
#pragma unroll
      for (int h4 = 0; h4 < HID / 4; ++h4) {
        float4 wv = *reinterpret_cast<const float4*>(wrow + h4 * 4);
        z[h4 * 4 + 0] = fmaf(s, wv.x, z[h4 * 4 + 0]);
        z[h4 * 4 + 1] = fmaf(s, wv.y, z[h4 * 4 + 1]);
        z[h4 * 4 + 2] = fmaf(s, wv.z, z[h4 * 4 + 2]);
        z[h4 * 4 + 3] = fmaf(s, wv.w, z[h4 * 4 + 3]);
      }
    }
  }
}

__device__ __forceinline__ void mv_reg(const float* __restrict__ v,
                                       const float* __restrict__ wlds,
                                       float z[HID]) {
#pragma unroll
  for (int h = 0; h < HID; ++h) z[h] = 0.f;
#pragma unroll
  for (int i = 0; i < HID; ++i) {
    float s = v[i];
    const float* wrow = wlds + i * HID;
#pragma unroll
    for (int h4 = 0; h4 < HID / 4; ++h4) {
      float4 wv = *reinterpret_cast<const float4*>(wrow + h4 * 4);
      z[h4 * 4 + 0] = fmaf(s, wv.x, z[h4 * 4 + 0]);
      z[h4 * 4 + 1] = fmaf(s, wv.y, z[h4 * 4 + 1]);
      z[h4 * 4 + 2] = fmaf(s, wv.z, z[h4 * 4 + 2]);
      z[h4 * 4 + 3] = fmaf(s, wv.w, z[h4 * 4 + 3]);
    }
  }
}

__device__ __forceinline__ void bn_params(const float* __restrict__ stats, int off,
                                          float cntInv, const float* __restrict__ g,
                                          const float* __restrict__ be,
                                          float* __restrict__ sc, float* __restrict__ sf) {
  if (threadIdx.x < HID) {
    int h = threadIdx.x;
    float mean = stats[off + h] * cntInv;
    float var = stats[off + HID + h] * cntInv - mean * mean;
    float s = g[h] * rsqrtf(var + BN_EPS);
    sc[h] = s;
    sf[h] = fmaf(-mean, s, be[h]);
  }
}

__device__ __forceinline__ void tile_accum(const float z[HID], float* __restrict__ tile,
                                           int h, int g, float& s, float& q) {
  int tid = threadIdx.x;
  __syncthreads();
#pragma unroll
  for (int j = 0; j < HID; ++j) tile[tid * 33 + j] = z[j];
  __syncthreads();
#pragma unroll
  for (int k = 0; k < 32; ++k) {
    float v = tile[(g * 32 + k) * 33 + h];
    s += v;
    q = fmaf(v, v, q);
  }
}

__device__ __forceinline__ void tile_finish(float* __restrict__ tile, int h, int g,
                                            float s, float q,
                                            float* __restrict__ gstats) {
  int tid = threadIdx.x;
  __syncthreads();
  tile[g * 32 + h] = s;
  tile[256 + g * 32 + h] = q;
  __syncthreads();
  if (tid < 64) {
    int hh = tid & 31;
    int base = (tid < 32) ? 0 : 256;
    float acc = 0.f;
#pragma unroll
    for (int g2 = 0; g2 < 8; ++g2) acc += tile[base + g2 * 32 + hh];
    atomicAdd(gstats + ((tid < 32) ? hh : (HID + hh)), acc);
  }
}

// ---------------------------------------------------------------------------
// sort infrastructure
__global__ __launch_bounds__(256) void kH(const int* __restrict__ ei,
                                          int* __restrict__ degS, int* __restrict__ degD) {
  int e = blockIdx.x * 256 + threadIdx.x;
  atomicAdd(degS + ei[e], 1);
  atomicAdd(degD + ei[N_EDGES + e], 1);
}

__global__ __launch_bounds__(1024) void kScan(const int* __restrict__ degS, int* __restrict__ baseS,
                                              const int* __restrict__ degD, int* __restrict__ baseD) {
  __shared__ int sc[1024];
  const int* deg = (blockIdx.x == 0) ? degS : degD;
  int* base = (blockIdx.x == 0) ? baseS : baseD;
  int t = threadIdx.x;
  const int C = 49;
  int st = t * C;
  int sum = 0;
  for (int k = 0; k < C; ++k) {
    int i = st + k;
    if (i < N_NODES) sum += deg[i];
  }
  sc[t] = sum;
  __syncthreads();
  for (int s = 1; s < 1024; s <<= 1) {
    int v = (t >= s) ? sc[t - s] : 0;
    __syncthreads();
    sc[t] += v;
    __syncthreads();
  }
  int run = sc[t] - sum;
  for (int k = 0; k < C; ++k) {
    int i = st + k;
    if (i < N_NODES) { base[i] = run; run += deg[i]; }
  }
  if (t == 1023) base[N_NODES] = run;
}

// posS[e] = src-sorted slot of edge e; combo[slot] = dstPos | (src&15)<<27
__global__ __launch_bounds__(256) void kRank(const int* __restrict__ ei,
    const int* __restrict__ baseS, const int* __restrict__ baseD,
    int* __restrict__ curS, int* __restrict__ curD,
    int* __restrict__ posS, unsigned* __restrict__ combo) {
  int e = blockIdx.x * 256 + threadIdx.x;
  int s = ei[e], d = ei[N_EDGES + e];
  int rs = atomicAdd(curS + s, 1);
  int ps = baseS[s] + rs;
  posS[e] = ps;
  int rd = atomicAdd(curD + d, 1);
  combo[ps] = (unsigned)(baseD[d] + rd) | ((unsigned)(s & 15) << 27);
}

// ---------------------------------------------------------------------------
// sM: M = sum_e ea ea^T (32x32) and easum = sum_e ea  (exact BN1 stats source)
__global__ __launch_bounds__(256) void sM_edge(const float* __restrict__ ea,
                                               float* __restrict__ M,
                                               float* __restrict__ easum) {
  __shared__ float t[256 * 36];
  int tid = threadIdx.x;
  int i = tid >> 3, j4 = tid & 7;
  float a0 = 0.f, a1 = 0.f, a2 = 0.f, a3 = 0.f, cs = 0.f;
#pragma unroll 1
  for (int tb = blockIdx.x; tb < ETILES; tb += gridDim.x) {
    __syncthreads();
    const float4* src = reinterpret_cast<const float4*>(ea + (size_t)tb * (256 * SD));
#pragma unroll
    for (int u = 0; u < 8; ++u) {
      int idx = u * 256 + tid;
      float4 v = src[idx];
      *reinterpret_cast<float4*>(&t[(idx >> 3) * 36 + (idx & 7) * 4]) = v;
    }
    __syncthreads();
#pragma unroll 4
    for (int k = 0; k < 256; ++k) {
      float s = t[k * 36 + i];
      float4 v = *reinterpret_cast<const float4*>(&t[k * 36 + j4 * 4]);
      a0 = fmaf(s, v.x, a0); a1 = fmaf(s, v.y, a1);
      a2 = fmaf(s, v.z, a2); a3 = fmaf(s, v.w, a3);
      if (j4 == 0) cs += s;
    }
  }
  atomicAdd(M + i * 32 + j4 * 4 + 0, a0);
  atomicAdd(M + i * 32 + j4 * 4 + 1, a1);
  atomicAdd(M + i * 32 + j4 * 4 + 2, a2);
  atomicAdd(M + i * 32 + j4 * 4 + 3, a3);
  if (j4 == 0) atomicAdd(easum + i, cs);
}

// kBN1: stats slot 0 closed-form: sum_h = easum.w1[:,h]; sumsq_h = w1^T M w1
__global__ __launch_bounds__(1024) void kBN1(const float* __restrict__ M,
                                             const float* __restrict__ easum,
                                             const float* __restrict__ w1,
                                             float* __restrict__ stats) {
  __shared__ float Ms[1024], w1s[1024], part[32 * 33];
  int tid = threadIdx.x;
  Ms[tid] = M[tid];
  w1s[tid] = w1[tid];
  __syncthreads();
  int h = tid & 31, i = tid >> 5;
  float tacc = 0.f;
#pragma unroll
  for (int j = 0; j < 32; ++j) tacc = fmaf(Ms[i * 32 + j], w1s[j * 32 + h], tacc);
  part[i * 33 + h] = w1s[i * 32 + h] * tacc;
  __syncthreads();
  if (tid < 32) {
    float sq = 0.f, sm = 0.f;
#pragma unroll
    for (int i2 = 0; i2 < 32; ++i2) {
      sq += part[i2 * 33 + tid];
      sm = fmaf(easum[i2], w1s[i2 * 32 + tid], sm);
    }
    stats[tid] = sm;
    stats[32 + tid] = sq;
  }
}

// ---------------------------------------------------------------------------
// S2e: z1 = ea@w1, h1 = relu(bn1), z2 = h1@w2; stats slot 1; h2s[posS[e]] = z2 (fp16)
__global__ __launch_bounds__(256) void s2_edge(
    const float* __restrict__ ea, const int* __restrict__ posS,
    const float* __restrict__ w1, const float* __restrict__ w2,
    const float* __restrict__ g1, const float* __restrict__ be1,
    float* __restrict__ stats, __half* __restrict__ h2s) {
  __shared__ float w1s[SD * HID], w2s[HID * HID];
  __shared__ float sc1[HID], sf1[HID];
  __shared__ float tile[256 * 33];
  for (int f = threadIdx.x; f < SD * HID; f += 256) w1s[f] = w1[f];
  for (int f = threadIdx.x; f < HID * HID; f += 256) w2s[f] = w2[f];
  bn_params(stats, 0, 1.f / N_EDGES, g1, be1, sc1, sf1);
  int h = threadIdx.x & 31, g = threadIdx.x >> 5;
  float s = 0.f, q = 0.f;
  __syncthreads();
#pragma unroll 1
  for (int t = blockIdx.x; t < ETILES; t += gridDim.x) {
    int e = t * 256 + threadIdx.x;
    const float4* rp = reinterpret_cast<const float4*>(ea + (size_t)e * SD);
    float z1[HID];
#pragma unroll
    for (int j = 0; j < HID; ++j) z1[j] = 0.f;
    mv_acc<8, 0>(rp, w1s, z1);
#pragma unroll
    for (int i = 0; i < HID; ++i) z1[i] = fmaxf(0.f, fmaf(z1[i], sc1[i], sf1[i]));
    float z2[HID];
    mv_reg(z1, w2s, z2);
    int ps = posS[e];
    unsigned us[16];
#pragma unroll
    for (int q2 = 0; q2 < 16; ++q2) us[q2] = pack2(z2[2 * q2], z2[2 * q2 + 1]);
    uint4* hp = reinterpret_cast<uint4*>(h2s + (size_t)ps * HID);
    hp[0] = make_uint4(us[0], us[1], us[2], us[3]);
    hp[1] = make_uint4(us[4], us[5], us[6], us[7]);
    hp[2] = make_uint4(us[8], us[9], us[10], us[11]);
    hp[3] = make_uint4(us[12], us[13], us[14], us[15]);
    tile_accum(z2, tile, h, g, s, q);
  }
  tile_finish(tile, h, g, s, q, stats + 64);
}

// ---------------------------------------------------------------------------
// K5-GEMM: block owns 16 src nodes; T + xb in LDS; coalesced slot loop;
// msg -> dst-sorted fp16 buffer.
__global__ __launch_bounds__(256) void k5_gemm(
    const float* __restrict__ x, const float* __restrict__ w3,
    const float* __restrict__ b3, const unsigned* __restrict__ combo,
    const int* __restrict__ baseS, const __half* __restrict__ h2s,
    const float* __restrict__ stats, const float* __restrict__ g2,
    const float* __restrict__ be2, __half* __restrict__ msgb) {
  __shared__ float Tl[16 * 516];
  __shared__ float xsl[16][33];
  __shared__ float xbl[256];
  __shared__ float b3s[SD * OC];
  __shared__ float sc2[HID], sf2[HID];
  __shared__ int jr[2];
  int tid = threadIdx.x;
  int n0 = blockIdx.x * 16;
  for (int f = tid; f < 16 * SD; f += 256)
    xsl[f >> 5][f & 31] = x[(size_t)n0 * SD + f];
  for (int f = tid; f < SD * OC; f += 256) b3s[f] = b3[f];
  if (tid == 0) jr[0] = baseS[n0];
  if (tid == 1) jr[1] = baseS[n0 + 16];
  bn_params(stats, 64, 1.f / N_EDGES, g2, be2, sc2, sf2);
  __syncthreads();
  // xb for the 16 nodes
  {
    int nl = tid >> 4, o = tid & 15;
    float a1 = 0.f;
#pragma unroll
    for (int i = 0; i < SD; ++i) a1 = fmaf(xsl[nl][i], b3s[i * OC + o], a1);
    xbl[tid] = a1;
  }
  // T rows
  {
    int oH = tid & 1, hh = (tid >> 1) & 31, ng = tid >> 6;
    float acc[4][8];
#pragma unroll
    for (int k = 0; k < 4; ++k)
#pragma unroll
      for (int j = 0; j < 8; ++j) acc[k][j] = 0.f;
    const float* wbase = w3 + hh * (SD * OC) + oH * 8;
#pragma unroll
    for (int i = 0; i < SD; ++i) {
      float4 wa = *reinterpret_cast<const float4*>(wbase + i * OC);
      float4 wb = *reinterpret_cast<const float4*>(wbase + i * OC + 4);
#pragma unroll
      for (int k = 0; k < 4; ++k) {
        float xv = xsl[ng * 4 + k][i];
        acc[k][0] = fmaf(xv, wa.x, acc[k][0]);
        acc[k][1] = fmaf(xv, wa.y, acc[k][1]);
        acc[k][2] = fmaf(xv, wa.z, acc[k][2]);
        acc[k][3] = fmaf(xv, wa.w, acc[k][3]);
        acc[k][4] = fmaf(xv, wb.x, acc[k][4]);
        acc[k][5] = fmaf(xv, wb.y, acc[k][5]);
        acc[k][6] = fmaf(xv, wb.z, acc[k][6]);
        acc[k][7] = fmaf(xv, wb.w, acc[k][7]);
      }
    }
#pragma unroll
    for (int k = 0; k < 4; ++k)
#pragma unroll
      for (int jj = 0; jj < 8; ++jj)
        Tl[(ng * 4 + k) * 516 + (oH * 8 + jj) * 32 + hh] = acc[k][jj];
  }
  __syncthreads();
  int jbeg = jr[0], jend = jr[1];
  for (int j = jbeg + tid; j < jend; j += 256) {
    unsigned c = combo[j];
    int dp = (int)(c & 0x07FFFFFFu);
    int nl = (int)(c >> 27);
    const uint4* hp = reinterpret_cast<const uint4*>(h2s + (size_t)j * HID);
    uint4 u0 = hp[0], u1 = hp[1], u2 = hp[2], u3 = hp[3];
    float h2v[HID];
    unpk8(u0, h2v + 0); unpk8(u1, h2v + 8);
    unpk8(u2, h2v + 16); unpk8(u3, h2v + 24);
#pragma unroll
    for (int k = 0; k < HID; ++k) h2v[k] = fmaxf(0.f, fmaf(h2v[k], sc2[k], sf2[k]));
    float m[OC];
#pragma unroll
    for (int o = 0; o < OC; ++o) m[o] = xbl[nl * 16 + o];
#pragma unroll
    for (int o = 0; o < OC; ++o) {
      const float* tb = Tl + nl * 516 + o * 32;
      float a = m[o];
#pragma unroll
      for (int h4 = 0; h4 < 8; ++h4) {
        float4 t = *reinterpret_cast<const float4*>(tb + h4 * 4);
        a = fmaf(h2v[h4 * 4 + 0], t.x, a);
        a = fmaf(h2v[h4 * 4 + 1], t.y, a);
        a = fmaf(h2v[h4 * 4 + 2], t.z, a);
        a = fmaf(h2v[h4 * 4 + 3], t.w, a);
      }
      m[o] = a;
    }
    unsigned us[8];
#pragma unroll
    for (int q = 0; q < 8; ++q) us[q] = pack2(m[2 * q], m[2 * q + 1]);
    uint4* mp = reinterpret_cast<uint4*>(msgb + (size_t)dp * OC);
    mp[0] = make_uint4(us[0], us[1], us[2], us[3]);
    mp[1] = make_uint4(us[4], us[5], us[6], us[7]);
  }
}

// ---------------------------------------------------------------------------
// K6: segment-sum + root term -> agg (=messages); fused own-L1 stats (slot 2)
__global__ __launch_bounds__(256) void k6_aggr_own(
    const int* __restrict__ baseD, const __half* __restrict__ msgb,
    const float* __restrict__ x, const float* __restrict__ rootw,
    const float* __restrict__ rootb, const float* __restrict__ ow1,
    float* __restrict__ agg, float* __restrict__ stats) {
  __shared__ float xsl[16][33];
  __shared__ float aggl[16 * 17];
  __shared__ float rws[SD * OC];
  __shared__ float ow1s[(SD + OC) * HID];
  __shared__ float zt[16 * 33];
  __shared__ float rbs[OC];
  int tid = threadIdx.x;
  int n0 = blockIdx.x * 16;
  for (int f = tid; f < 16 * SD; f += 256) xsl[f >> 5][f & 31] = x[(size_t)n0 * SD + f];
  for (int f = tid; f < SD * OC; f += 256) rws[f] = rootw[f];
  for (int f = tid; f < (SD + OC) * HID; f += 256) ow1s[f] = ow1[f];
  if (tid < OC) rbs[tid] = rootb[tid];
  __syncthreads();
  int nl = tid >> 4, o = tid & 15;
  int d = n0 + nl;
  float r = rbs[o];
#pragma unroll
  for (int i = 0; i < SD; ++i) r = fmaf(xsl[nl][i], rws[i * OC + o], r);
  int b0 = baseD[d], b1 = baseD[d + 1];
  float s = 0.f;
  for (int j = b0; j < b1; ++j) s += __half2float(msgb[(size_t)j * OC + o]);
  float val = r + s;
  agg[(size_t)d * OC + o] = val;
  aggl[nl * 17 + o] = val;
  __syncthreads();
  float za = 0.f, zb = 0.f;
#pragma unroll
  for (int i = 0; i < SD; ++i) {
    float xv = xsl[nl][i];
    za = fmaf(xv, ow1s[i * HID + o], za);
    zb = fmaf(xv, ow1s[i * HID + o + 16], zb);
  }
#pragma unroll
  for (int i = 0; i < OC; ++i) {
    float mv = aggl[nl * 17 + i];
    za = fmaf(mv, ow1s[(SD + i) * HID + o], za);
    zb = fmaf(mv, ow1s[(SD + i) * HID + o + 16], zb);
  }
  zt[nl * 33 + o] = za;
  zt[nl * 33 + o + 16] = zb;
  __syncthreads();
  if (tid < 64) {
    int h = tid & 31;
    bool issq = tid >= 32;
    float acc = 0.f;
#pragma unroll
    for (int k = 0; k < 16; ++k) {
      float v = zt[k * 33 + h];
      acc += issq ? v * v : v;
    }
    atomicAdd(stats + 128 + (issq ? 32 : 0) + h, acc);
  }
}

// ---------------------------------------------------------------------------
__global__ __launch_bounds__(256) void s2_own(
    const float* __restrict__ x, const float* __restrict__ msgs,
    const float* __restrict__ w1, const float* __restrict__ w2,
    const float* __restrict__ g1, const float* __restrict__ be1,
    float* __restrict__ stats) {
  __shared__ float w1s[(SD + OC) * HID], w2s[HID * HID];
  __shared__ float sc1[HID], sf1[HID];
  __shared__ float tile[256 * 33];
  for (int f = threadIdx.x; f < (SD + OC) * HID; f += 256) w1s[f] = w1[f];
  for (int f = threadIdx.x; f < HID * HID; f += 256) w2s[f] = w2[f];
  bn_params(stats, 128, 1.f / N_NODES, g1, be1, sc1, sf1);
  int h = threadIdx.x & 31, g = threadIdx.x >> 5;
  float s = 0.f, q = 0.f;
  __syncthreads();
#pragma unroll 1
  for (int t = blockIdx.x; t < NTILES; t += gridDim.x) {
    int n = t * 256 + threadIdx.x;
    float z2[HID];
#pragma unroll
    for (int j = 0; j < HID; ++j) z2[j] = 0.f;
    if (n < N_NODES) {
      const float4* xp = reinterpret_cast<const float4*>(x + (size_t)n * SD);
      const float4* mp = reinterpret_cast<const float4*>(msgs + (size_t)n * OC);
      float z1[HID];
#pragma unroll
      for (int j = 0; j < HID; ++j) z1[j] = 0.f;
      mv_acc<8, 0>(xp, w1s, z1);
      mv_acc<4, SD>(mp, w1s, z1);
#pragma unroll
      for (int i = 0; i < HID; ++i) z1[i] = fmaxf(0.f, fmaf(z1[i], sc1[i], sf1[i]));
      mv_reg(z1, w2s, z2);
    }
    tile_accum(z2, tile, h, g, s, q);
  }
  tile_finish(tile, h, g, s, q, stats + 192);
}

__global__ __launch_bounds__(256) void k10_own_out(
    const float* __restrict__ x, const float* __restrict__ msgs,
    const float* __restrict__ w1, const float* __restrict__ w2,
    const float* __restrict__ w3o, const float* __restrict__ b3o,
    const float* __restrict__ g1, const float* __restrict__ be1,
    const float* __restrict__ g2, const float* __restrict__ be2,
    const float* __restrict__ stats, float* __restrict__ out) {
  __shared__ float w1s[(SD + OC) * HID], w2s[HID * HID], w3s[HID * SD];
  __shared__ float sc1[HID], sf1[HID], sc2[HID], sf2[HID];
  for (int f = threadIdx.x; f < (SD + OC) * HID; f += 256) w1s[f] = w1[f];
  for (int f = threadIdx.x; f < HID * HID; f += 256) w2s[f] = w2[f];
  for (int f = threadIdx.x; f < HID * SD; f += 256) w3s[f] = w3o[f];
  bn_params(stats, 128, 1.f / N_NODES, g1, be1, sc1, sf1);
  bn_params(stats, 192, 1.f / N_NODES, g2, be2, sc2, sf2);
  __syncthreads();
  int n = blockIdx.x * 256 + threadIdx.x;
  if (n >= N_NODES) return;
  const float4* xp = reinterpret_cast<const float4*>(x + (size_t)n * SD);
  const float4* mp = reinterpret_cast<const float4*>(msgs + (size_t)n * OC);
  float z1[HID];
#pragma unroll
  for (int j = 0; j < HID; ++j) z1[j] = 0.f;
  mv_acc<8, 0>(xp, w1s, z1);
  mv_acc<4, SD>(mp, w1s, z1);
#pragma unroll
  for (int i = 0; i < HID; ++i) z1[i] = fmaxf(0.f, fmaf(z1[i], sc1[i], sf1[i]));
  float z2[HID];
  mv_reg(z1, w2s, z2);
#pragma unroll
  for (int i = 0; i < HID; ++i) z2[i] = fmaxf(0.f, fmaf(z2[i], sc2[i], sf2[i]));
  float z3[HID];
  mv_reg(z2, w3s, z3);
  float4* op = reinterpret_cast<float4*>(out + (size_t)n * SD);
#pragma unroll
  for (int j4 = 0; j4 < 8; ++j4) {
    op[j4] = make_float4(z3[j4 * 4 + 0] + b3o[j4 * 4 + 0],
                         z3[j4 * 4 + 1] + b3o[j4 * 4 + 1],
                         z3[j4 * 4 + 2] + b3o[j4 * 4 + 2],
                         z3[j4 * 4 + 3] + b3o[j4 * 4 + 3]);
  }
}

extern "C" void kernel_launch(void* const* d_in, const int* in_sizes, int n_in,
                              void* d_out, int out_size, void* d_ws, size_t ws_size,
                              hipStream_t stream) {
  const float* x    = (const float*)d_in[0];
  const float* ea   = (const float*)d_in[1];
  const int*   ei   = (const int*)d_in[2];
  const float* mw1  = (const float*)d_in[3];
  const float* mg1  = (const float*)d_in[5];
  const float* mbe1 = (const float*)d_in[6];
  const float* mw2  = (const float*)d_in[7];
  const float* mg2  = (const float*)d_in[9];
  const float* mbe2 = (const float*)d_in[10];
  const float* mw3  = (const float*)d_in[11];
  const float* mb3  = (const float*)d_in[12];
  const float* rw   = (const float*)d_in[13];
  const float* rb   = (const float*)d_in[14];
  const float* ow1  = (const float*)d_in[15];
  const float* og1  = (const float*)d_in[17];
  const float* obe1 = (const float*)d_in[18];
  const float* ow2  = (const float*)d_in[19];
  const float* og2  = (const float*)d_in[21];
  const float* obe2 = (const float*)d_in[22];
  const float* ow3  = (const float*)d_in[23];
  const float* ob3  = (const float*)d_in[24];
  float* out = (float*)d_out;

  char* ws = (char*)d_ws;
  float* stats  = (float*)(ws + OFF_STATS);
  float* M      = (float*)(ws + OFF_M);
  float* easum  = (float*)(ws + OFF_EASUM);
  int* degS     = (int*)(ws + OFF_DEGS);
  int* curS     = (int*)(ws + OFF_CURS);
  int* degD     = (int*)(ws + OFF_DEGD);
  int* curD     = (int*)(ws + OFF_CURD);
  int* baseS    = (int*)(ws + OFF_BASES);
  int* baseD    = (int*)(ws + OFF_BASED);
  int* posS     = (int*)(ws + OFF_POSS);
  unsigned* combo = (unsigned*)(ws + OFF_COMBO);
  float* agg    = (float*)(ws + OFF_AGG);
  __half* h2s   = (__half*)(ws + OFF_H2S);
  __half* msgb  = (__half*)(ws + OFF_MSGB);

  hipMemsetAsync(ws, 0, 805376, stream);

  kH<<<3125, 256, 0, stream>>>(ei, degS, degD);
  kScan<<<2, 1024, 0, stream>>>(degS, baseS, degD, baseD);
  kRank<<<3125, 256, 0, stream>>>(ei, baseS, baseD, curS, curD, posS, combo);
  sM_edge<<<1024, 256, 0, stream>>>(ea, M, easum);
  kBN1<<<1, 1024, 0, stream>>>(M, easum, mw1, stats);
  s2_edge<<<1024, 256, 0, stream>>>(ea, posS, mw1, mw2, mg1, mbe1, stats, h2s);
  k5_gemm<<<3125, 256, 0, stream>>>(x, mw3, mb3, combo, baseS, h2s,
                                    stats, mg2, mbe2, msgb);
  k6_aggr_own<<<3125, 256, 0, stream>>>(baseD, msgb, x, rw, rb, ow1, agg, stats);
  s2_own<<<NTILES, 256, 0, stream>>>(x, agg, ow1, ow2, og1, obe1, stats);
  k10_own_out<<<(N_NODES + 255) / 256, 256, 0, stream>>>(
      x, agg, ow1, ow2, ow3, ob3, og1, obe1, og2, obe2, stats, out);
}

// Round 6
// 733.028 us; speedup vs baseline: 1.1648x; 1.1648x over previous
//
#include <hip/hip_runtime.h>
#include <hip/hip_fp16.h>

// NNConv particle GNN, round 6 (= round 5 + h2-store coverage fix):
//  - edge MLP via MFMA 32x32x16_f16 with split-fp16 3-term precision
//    (weights in VGPR B-fragments; no LDS in the GEMM inner loop)
//  - sE<0>: BN1 stats (exact z1 via split mfma, per-lane C-layout partials)
//  - sE<1>: recompute z1, BN1+ReLU, L2 mfma, BN2 stats, h2 -> fp16 scatter
//    FIX: store BOTH uint4s per lane (16 halves) -- round 5 stored only 8,
//    leaving channels 8-15/24-31 of every edge stale (absmax 4.3).
// BN training mode => linear biases b1/b2/own_b1/own_b2 cancel exactly.

#define N_NODES 50000
#define N_EDGES 800000
#define SD 32
#define OC 16
#define HID 32
#define BN_EPS 1e-5f
#define NTILES 196    // ceil(50000/256)

// ---- workspace byte offsets (64B-aligned) ----
#define OFF_STATS 0u          // 256 f
#define OFF_DEGS  5376u       // 50000 i
#define OFF_CURS  205376u
#define OFF_DEGD  405376u
#define OFF_CURD  605376u     // memset [0, 805376)
#define OFF_BASES 805376u     // 50001 i
#define OFF_BASED 1005440u    // 50001 i
#define OFF_POSS  1205504u    // 800000 i
#define OFF_COMBO 4405504u    // 800000 u
#define OFF_AGG   7605504u    // 800000 f
#define OFF_H2S   10805504u   // 25.6M half
#define OFF_MSGB  62005504u   // 12.8M half

typedef _Float16 f16x8 __attribute__((ext_vector_type(8)));
typedef float f32x16 __attribute__((ext_vector_type(16)));

__device__ __forceinline__ float f4get(const float4& v, int ii) {
  return ii == 0 ? v.x : ii == 1 ? v.y : ii == 2 ? v.z : v.w;
}

__device__ __forceinline__ unsigned pack2(float a, float b) {
  __half2 h = __floats2half2_rn(a, b);
  return *reinterpret_cast<unsigned*>(&h);
}
__device__ __forceinline__ void unpk8(uint4 u, float* o) {
  __half2 a = *reinterpret_cast<__half2*>(&u.x), b = *reinterpret_cast<__half2*>(&u.y);
  __half2 c = *reinterpret_cast<__half2*>(&u.z), d = *reinterpret_cast<__half2*>(&u.w);
  float2 fa = __half22float2(a), fb = __half22float2(b);
  float2 fc = __half22float2(c), fd = __half22float2(d);
  o[0] = fa.x; o[1] = fa.y; o[2] = fb.x; o[3] = fb.y;
  o[4] = fc.x; o[5] = fc.y; o[6] = fd.x; o[7] = fd.y;
}

template<int I4, int IOFF>
__device__ __forceinline__ void mv_acc(const float4* __restrict__ rp,
                                       const float* __restrict__ wlds,
                                       float z[HID]) {
#pragma unroll
  for (int i4 = 0; i4 < I4; ++i4) {
    float4 rv = rp[i4];
#pragma unroll
    for (int ii = 0; ii < 4; ++ii) {
      float s = f4get(rv, ii);
      const float* wrow = wlds + (IOFF + i4 * 4 + ii) * HID;
#pragma unroll
      for (int h4 = 0; h4 < HID / 4; ++h4) {
        float4 wv = *reinterpret_cast<const float4*>(wrow + h4 * 4);
        z[h4 * 4 + 0] = fmaf(s, wv.x, z[h4 * 4 + 0]);
        z[h4 * 4 + 1] = fmaf(s, wv.y, z[h4 * 4 + 1]);
        z[h4 * 4 + 2] = fmaf(s, wv.z, z[h4 * 4 + 2]);
        z[h4 * 4 + 3] = fmaf(s, wv.w, z[h4 * 4 + 3]);
      }
    }
  }
}

__device__ __forceinline__ void mv_reg(const float* __restrict__ v,
                                       const float* __restrict__ wlds,
                                       float z[HID]) {
#pragma unroll
  for (int h = 0; h < HID; ++h) z[h] = 0.f;
#pragma unroll
  for (int i = 0; i < HID; ++i) {
    float s = v[i];
    const float* wrow = wlds + i * HID;
#pragma unroll
    for (int h4 = 0; h4 < HID / 4; ++h4) {
      float4 wv = *reinterpret_cast<const float4*>(wrow + h4 * 4);
      z[h4 * 4 + 0] = fmaf(s, wv.x, z[h4 * 4 + 0]);
      z[h4 * 4 + 1] = fmaf(s, wv.y, z[h4 * 4 + 1]);
      z[h4 * 4 + 2] = fmaf(s, wv.z, z[h4 * 4 + 2]);
      z[h4 * 4 + 3] = fmaf(s, wv.w, z[h4 * 4 + 3]);
    }
  }
}

__device__ __forceinline__ void bn_params(const float* __restrict__ stats, int off,
                                          float cntInv, const float* __restrict__ g,
                                          const float* __restrict__ be,
                                          float* __restrict__ sc, float* __restrict__ sf) {
  if (threadIdx.x < HID) {
    int h = threadIdx.x;
    float mean = stats[off + h] * cntInv;
    float var = stats[off + HID + h] * cntInv - mean * mean;
    float s = g[h] * rsqrtf(var + BN_EPS);
    sc[h] = s;
    sf[h] = fmaf(-mean, s, be[h]);
  }
}

__device__ __forceinline__ void tile_accum(const float z[HID], float* __restrict__ tile,
                                           int h, int g, float& s, float& q) {
  int tid = threadIdx.x;
  __syncthreads();
#pragma unroll
  for (int j = 0; j < HID; ++j) tile[tid * 33 + j] = z[j];
  __syncthreads();
#pragma unroll
  for (int k = 0; k < 32; ++k) {
    float v = tile[(g * 32 + k) * 33 + h];
    s += v;
    q = fmaf(v, v, q);
  }
}

__device__ __forceinline__ void tile_finish(float* __restrict__ tile, int h, int g,
                                            float s, float q,
                                            float* __restrict__ gstats) {
  int tid = threadIdx.x;
  __syncthreads();
  tile[g * 32 + h] = s;
  tile[256 + g * 32 + h] = q;
  __syncthreads();
  if (tid < 64) {
    int hh = tid & 31;
    int base = (tid < 32) ? 0 : 256;
    float acc = 0.f;
#pragma unroll
    for (int g2 = 0; g2 < 8; ++g2) acc += tile[base + g2 * 32 + hh];
    atomicAdd(gstats + ((tid < 32) ? hh : (HID + hh)), acc);
  }
}

// ---------------------------------------------------------------------------
// sort infrastructure
__global__ __launch_bounds__(256) void kH(const int* __restrict__ ei,
                                          int* __restrict__ degS, int* __restrict__ degD) {
  int e = blockIdx.x * 256 + threadIdx.x;
  atomicAdd(degS + ei[e], 1);
  atomicAdd(degD + ei[N_EDGES + e], 1);
}

__global__ __launch_bounds__(1024) void kScan(const int* __restrict__ degS, int* __restrict__ baseS,
                                              const int* __restrict__ degD, int* __restrict__ baseD) {
  __shared__ int sc[1024];
  const int* deg = (blockIdx.x == 0) ? degS : degD;
  int* base = (blockIdx.x == 0) ? baseS : baseD;
  int t = threadIdx.x;
  const int C = 49;
  int st = t * C;
  int sum = 0;
  for (int k = 0; k < C; ++k) {
    int i = st + k;
    if (i < N_NODES) sum += deg[i];
  }
  sc[t] = sum;
  __syncthreads();
  for (int s = 1; s < 1024; s <<= 1) {
    int v = (t >= s) ? sc[t - s] : 0;
    __syncthreads();
    sc[t] += v;
    __syncthreads();
  }
  int run = sc[t] - sum;
  for (int k = 0; k < C; ++k) {
    int i = st + k;
    if (i < N_NODES) { base[i] = run; run += deg[i]; }
  }
  if (t == 1023) base[N_NODES] = run;
}

__global__ __launch_bounds__(256) void kRank(const int* __restrict__ ei,
    const int* __restrict__ baseS, const int* __restrict__ baseD,
    int* __restrict__ curS, int* __restrict__ curD,
    int* __restrict__ posS, unsigned* __restrict__ combo) {
  int e = blockIdx.x * 256 + threadIdx.x;
  int s = ei[e], d = ei[N_EDGES + e];
  int rs = atomicAdd(curS + s, 1);
  int ps = baseS[s] + rs;
  posS[e] = ps;
  int rd = atomicAdd(curD + d, 1);
  combo[ps] = (unsigned)(baseD[d] + rd) | ((unsigned)(s & 15) << 27);
}

// ---------------------------------------------------------------------------
// sE<PHASE>: edge MLP via MFMA, split-fp16 3-term precision.
// C/D (32x32): lane l holds D[row=(r&3)+8*(r>>2)+4*(l>>5)][col=l&31]  [HW-verified]
// A/B slot fill uses k = kf*16 + (l>>5)*8 + j consistently for A and B
// (any consistent bijective slot fill yields the correct k-sum).
// PHASE 0: accumulate z1 sum/sumsq -> stats slot 0.
// PHASE 1: h1=relu(bn1(z1)); z2=h1@w2 (w2 split); stats slot 1; h2s[posS]=z2 fp16.
template<int PHASE>
__global__ __launch_bounds__(256) void sE(
    const float* __restrict__ ea, const int* __restrict__ posS,
    const float* __restrict__ w1, const float* __restrict__ w2,
    const float* __restrict__ g1, const float* __restrict__ be1,
    float* __restrict__ stats, __half* __restrict__ h2s) {
  __shared__ _Float16 xpose[4][32 * 40];   // per-wave transpose buffer
  __shared__ float sred[4][2][32];
  int tid = threadIdx.x;
  int lane = tid & 63, wid = tid >> 6;
  int lr = lane & 31, lh = lane >> 5;

  // B fragments (loaded once, live in VGPRs)
  f16x8 w1h[2], w1l[2], w2h[2], w2l[2];
#pragma unroll
  for (int kf = 0; kf < 2; ++kf) {
#pragma unroll
    for (int j = 0; j < 8; ++j) {
      int k = kf * 16 + lh * 8 + j;
      float v = w1[k * HID + lr];
      _Float16 hi = (_Float16)v;
      w1h[kf][j] = hi;
      w1l[kf][j] = (_Float16)(v - (float)hi);
      if (PHASE == 1) {
        float u = w2[k * HID + lr];
        _Float16 uh = (_Float16)u;
        w2h[kf][j] = uh;
        w2l[kf][j] = (_Float16)(u - (float)uh);
      } else {
        w2h[kf][j] = (_Float16)0.f;
        w2l[kf][j] = (_Float16)0.f;
      }
    }
  }
  float sc1 = 0.f, sf1 = 0.f;
  if (PHASE == 1) {
    float mean = stats[lr] * (1.f / N_EDGES);
    float var = stats[32 + lr] * (1.f / N_EDGES) - mean * mean;
    float s = g1[lr] * rsqrtf(var + BN_EPS);
    sc1 = s;
    sf1 = fmaf(-mean, s, be1[lr]);
  }
  float ssum = 0.f, ssq = 0.f;
  _Float16* xp = xpose[wid];

  for (int t = blockIdx.x * 4 + wid; t < N_EDGES / 32; t += gridDim.x * 4) {
    int e0 = t * 32;
    // A fragments for L1 (split fp16)
    f16x8 ah[2], al[2];
#pragma unroll
    for (int kf = 0; kf < 2; ++kf) {
      const float4* p = reinterpret_cast<const float4*>(
          ea + (size_t)(e0 + lr) * SD + kf * 16 + lh * 8);
      float4 v0 = p[0], v1 = p[1];
      float vv[8] = {v0.x, v0.y, v0.z, v0.w, v1.x, v1.y, v1.z, v1.w};
#pragma unroll
      for (int j = 0; j < 8; ++j) {
        _Float16 hi = (_Float16)vv[j];
        ah[kf][j] = hi;
        al[kf][j] = (_Float16)(vv[j] - (float)hi);
      }
    }
    f32x16 acc = {};
#pragma unroll
    for (int kf = 0; kf < 2; ++kf) {
      acc = __builtin_amdgcn_mfma_f32_32x32x16_f16(ah[kf], w1h[kf], acc, 0, 0, 0);
      acc = __builtin_amdgcn_mfma_f32_32x32x16_f16(al[kf], w1h[kf], acc, 0, 0, 0);
      acc = __builtin_amdgcn_mfma_f32_32x32x16_f16(ah[kf], w1l[kf], acc, 0, 0, 0);
    }
    if (PHASE == 0) {
#pragma unroll
      for (int r = 0; r < 16; ++r) {
        ssum += acc[r];
        ssq = fmaf(acc[r], acc[r], ssq);
      }
    } else {
      // h1 = relu(bn1(z1)) -> LDS row-major [edge-row][h] fp16
#pragma unroll
      for (int r = 0; r < 16; ++r) {
        int row = (r & 3) + 8 * (r >> 2) + 4 * lh;
        float h1 = fmaxf(0.f, fmaf(acc[r], sc1, sf1));
        xp[row * 40 + lr] = (_Float16)h1;
      }
      __builtin_amdgcn_sched_barrier(0);
      asm volatile("s_waitcnt lgkmcnt(0)" ::: "memory");
      __builtin_amdgcn_sched_barrier(0);
      f32x16 acc2 = {};
#pragma unroll
      for (int kf = 0; kf < 2; ++kf) {
        f16x8 a2 = *reinterpret_cast<const f16x8*>(xp + lr * 40 + kf * 16 + lh * 8);
        acc2 = __builtin_amdgcn_mfma_f32_32x32x16_f16(a2, w2h[kf], acc2, 0, 0, 0);
        acc2 = __builtin_amdgcn_mfma_f32_32x32x16_f16(a2, w2l[kf], acc2, 0, 0, 0);
      }
#pragma unroll
      for (int r = 0; r < 16; ++r) {
        ssum += acc2[r];
        ssq = fmaf(acc2[r], acc2[r], ssq);
      }
      // z2 -> LDS row-major fp16, then coalesced-per-edge scatter to h2s[posS]
      __builtin_amdgcn_sched_barrier(0);
      asm volatile("s_waitcnt lgkmcnt(0)" ::: "memory");
      __builtin_amdgcn_sched_barrier(0);
#pragma unroll
      for (int r = 0; r < 16; ++r) {
        int row = (r & 3) + 8 * (r >> 2) + 4 * lh;
        xp[row * 40 + lr] = (_Float16)acc2[r];
      }
      __builtin_amdgcn_sched_barrier(0);
      asm volatile("s_waitcnt lgkmcnt(0)" ::: "memory");
      __builtin_amdgcn_sched_barrier(0);
      // FIX: each lane stores 16 halves (2 x uint4) covering channels
      // [lh*16, lh*16+16) of edge lr. Round 5 stored only the first uint4.
      int ps = posS[e0 + lr];
      uint4 va = *reinterpret_cast<const uint4*>(xp + lr * 40 + lh * 16);
      uint4 vb = *reinterpret_cast<const uint4*>(xp + lr * 40 + lh * 16 + 8);
      __half* dst = (__half*)h2s + (size_t)ps * HID + lh * 16;
      *reinterpret_cast<uint4*>(dst) = va;
      *reinterpret_cast<uint4*>(dst + 8) = vb;
      __builtin_amdgcn_sched_barrier(0);
    }
  }
  // block reduction of per-lane (ssum, ssq) -> 64 atomics
  ssum += __shfl_xor(ssum, 32);
  ssq += __shfl_xor(ssq, 32);
  if (lane < 32) {
    sred[wid][0][lane] = ssum;
    sred[wid][1][lane] = ssq;
  }
  __syncthreads();
  if (tid < 64) {
    int h = tid & 31, part = tid >> 5;
    float a = sred[0][part][h] + sred[1][part][h] + sred[2][part][h] + sred[3][part][h];
    atomicAdd(stats + (PHASE == 0 ? 0 : 64) + part * 32 + h, a);
  }
}

// ---------------------------------------------------------------------------
// K5-GEMM: block owns 16 src nodes; T + xb in LDS; coalesced slot loop;
// msg -> dst-sorted fp16 buffer.
__global__ __launch_bounds__(256) void k5_gemm(
    const float* __restrict__ x, const float* __restrict__ w3,
    const float* __restrict__ b3, const unsigned* __restrict__ combo,
    const int* __restrict__ baseS, const __half* __restrict__ h2s,
    const float* __restrict__ stats, const float* __restrict__ g2,
    const float* __restrict__ be2, __half* __restrict__ msgb) {
  __shared__ float Tl[16 * 516];
  __shared__ float xsl[16][33];
  __shared__ float xbl[256];
  __shared__ float b3s[SD * OC];
  __shared__ float sc2[HID], sf2[HID];
  __shared__ int jr[2];
  int tid = threadIdx.x;
  int n0 = blockIdx.x * 16;
  for (int f = tid; f < 16 * SD; f += 256)
    xsl[f >> 5][f & 31] = x[(size_t)n0 * SD + f];
  for (int f = tid; f < SD * OC; f += 256) b3s[f] = b3[f];
  if (tid == 0) jr[0] = baseS[n0];
  if (tid == 1) jr[1] = baseS[n0 + 16];
  bn_params(stats, 64, 1.f / N_EDGES, g2, be2, sc2, sf2);
  __syncthreads();
  {
    int nl = tid >> 4, o = tid & 15;
    float a1 = 0.f;
#pragma unroll
    for (int i = 0; i < SD; ++i) a1 = fmaf(xsl[nl][i], b3s[i * OC + o], a1);
    xbl[tid] = a1;
  }
  {
    int oH = tid & 1, hh = (tid >> 1) & 31, ng = tid >> 6;
    float acc[4][8];
#pragma unroll
    for (int k = 0; k < 4; ++k)
#pragma unroll
      for (int j = 0; j < 8; ++j) acc[k][j] = 0.f;
    const float* wbase = w3 + hh * (SD * OC) + oH * 8;
#pragma unroll
    for (int i = 0; i < SD; ++i) {
      float4 wa = *reinterpret_cast<const float4*>(wbase + i * OC);
      float4 wb = *reinterpret_cast<const float4*>(wbase + i * OC + 4);
#pragma unroll
      for (int k = 0; k < 4; ++k) {
        float xv = xsl[ng * 4 + k][i];
        acc[k][0] = fmaf(xv, wa.x, acc[k][0]);
        acc[k][1] = fmaf(xv, wa.y, acc[k][1]);
        acc[k][2] = fmaf(xv, wa.z, acc[k][2]);
        acc[k][3] = fmaf(xv, wa.w, acc[k][3]);
        acc[k][4] = fmaf(xv, wb.x, acc[k][4]);
        acc[k][5] = fmaf(xv, wb.y, acc[k][5]);
        acc[k][6] = fmaf(xv, wb.z, acc[k][6]);
        acc[k][7] = fmaf(xv, wb.w, acc[k][7]);
      }
    }
#pragma unroll
    for (int k = 0; k < 4; ++k)
#pragma unroll
      for (int jj = 0; jj < 8; ++jj)
        Tl[(ng * 4 + k) * 516 + (oH * 8 + jj) * 32 + hh] = acc[k][jj];
  }
  __syncthreads();
  int jbeg = jr[0], jend = jr[1];
  for (int j = jbeg + tid; j < jend; j += 256) {
    unsigned c = combo[j];
    int dp = (int)(c & 0x07FFFFFFu);
    int nl = (int)(c >> 27);
    const uint4* hp = reinterpret_cast<const uint4*>(h2s + (size_t)j * HID);
    uint4 u0 = hp[0], u1 = hp[1], u2 = hp[2], u3 = hp[3];
    float h2v[HID];
    unpk8(u0, h2v + 0); unpk8(u1, h2v + 8);
    unpk8(u2, h2v + 16); unpk8(u3, h2v + 24);
#pragma unroll
    for (int k = 0; k < HID; ++k) h2v[k] = fmaxf(0.f, fmaf(h2v[k], sc2[k], sf2[k]));
    float m[OC];
#pragma unroll
    for (int o = 0; o < OC; ++o) m[o] = xbl[nl * 16 + o];
#pragma unroll
    for (int o = 0; o < OC; ++o) {
      const float* tb = Tl + nl * 516 + o * 32;
      float a = m[o];
#pragma unroll
      for (int h4 = 0; h4 < 8; ++h4) {
        float4 t = *reinterpret_cast<const float4*>(tb + h4 * 4);
        a = fmaf(h2v[h4 * 4 + 0], t.x, a);
        a = fmaf(h2v[h4 * 4 + 1], t.y, a);
        a = fmaf(h2v[h4 * 4 + 2], t.z, a);
        a = fmaf(h2v[h4 * 4 + 3], t.w, a);
      }
      m[o] = a;
    }
    unsigned us[8];
#pragma unroll
    for (int q = 0; q < 8; ++q) us[q] = pack2(m[2 * q], m[2 * q + 1]);
    uint4* mp = reinterpret_cast<uint4*>(msgb + (size_t)dp * OC);
    mp[0] = make_uint4(us[0], us[1], us[2], us[3]);
    mp[1] = make_uint4(us[4], us[5], us[6], us[7]);
  }
}

// ---------------------------------------------------------------------------
// K6: segment-sum + root term -> agg (=messages); fused own-L1 stats (slot 2)
__global__ __launch_bounds__(256) void k6_aggr_own(
    const int* __restrict__ baseD, const __half* __restrict__ msgb,
    const float* __restrict__ x, const float* __restrict__ rootw,
    const float* __restrict__ rootb, const float* __restrict__ ow1,
    float* __restrict__ agg, float* __restrict__ stats) {
  __shared__ float xsl[16][33];
  __shared__ float aggl[16 * 17];
  __shared__ float rws[SD * OC];
  __shared__ float ow1s[(SD + OC) * HID];
  __shared__ float zt[16 * 33];
  __shared__ float rbs[OC];
  int tid = threadIdx.x;
  int n0 = blockIdx.x * 16;
  for (int f = tid; f < 16 * SD; f += 256) xsl[f >> 5][f & 31] = x[(size_t)n0 * SD + f];
  for (int f = tid; f < SD * OC; f += 256) rws[f] = rootw[f];
  for (int f = tid; f < (SD + OC) * HID; f += 256) ow1s[f] = ow1[f];
  if (tid < OC) rbs[tid] = rootb[tid];
  __syncthreads();
  int nl = tid >> 4, o = tid & 15;
  int d = n0 + nl;
  float r = rbs[o];
#pragma unroll
  for (int i = 0; i < SD; ++i) r = fmaf(xsl[nl][i], rws[i * OC + o], r);
  int b0 = baseD[d], b1 = baseD[d + 1];
  float s = 0.f;
  for (int j = b0; j < b1; ++j) s += __half2float(msgb[(size_t)j * OC + o]);
  float val = r + s;
  agg[(size_t)d * OC + o] = val;
  aggl[nl * 17 + o] = val;
  __syncthreads();
  float za = 0.f, zb = 0.f;
#pragma unroll
  for (int i = 0; i < SD; ++i) {
    float xv = xsl[nl][i];
    za = fmaf(xv, ow1s[i * HID + o], za);
    zb = fmaf(xv, ow1s[i * HID + o + 16], zb);
  }
#pragma unroll
  for (int i = 0; i < OC; ++i) {
    float mv = aggl[nl * 17 + i];
    za = fmaf(mv, ow1s[(SD + i) * HID + o], za);
    zb = fmaf(mv, ow1s[(SD + i) * HID + o + 16], zb);
  }
  zt[nl * 33 + o] = za;
  zt[nl * 33 + o + 16] = zb;
  __syncthreads();
  if (tid < 64) {
    int h = tid & 31;
    bool issq = tid >= 32;
    float acc = 0.f;
#pragma unroll
    for (int k = 0; k < 16; ++k) {
      float v = zt[k * 33 + h];
      acc += issq ? v * v : v;
    }
    atomicAdd(stats + 128 + (issq ? 32 : 0) + h, acc);
  }
}

// ---------------------------------------------------------------------------
__global__ __launch_bounds__(256) void s2_own(
    const float* __restrict__ x, const float* __restrict__ msgs,
    const float* __restrict__ w1, const float* __restrict__ w2,
    const float* __restrict__ g1, const float* __restrict__ be1,
    float* __restrict__ stats) {
  __shared__ float w1s[(SD + OC) * HID], w2s[HID * HID];
  __shared__ float sc1[HID], sf1[HID];
  __shared__ float tile[256 * 33];
  for (int f = threadIdx.x; f < (SD + OC) * HID; f += 256) w1s[f] = w1[f];
  for (int f = threadIdx.x; f < HID * HID; f += 256) w2s[f] = w2[f];
  bn_params(stats, 128, 1.f / N_NODES, g1, be1, sc1, sf1);
  int h = threadIdx.x & 31, g = threadIdx.x >> 5;
  float s = 0.f, q = 0.f;
  __syncthreads();
#pragma unroll 1
  for (int t = blockIdx.x; t < NTILES; t += gridDim.x) {
    int n = t * 256 + threadIdx.x;
    float z2[HID];
#pragma unroll
    for (int j = 0; j < HID; ++j) z2[j] = 0.f;
    if (n < N_NODES) {
      const float4* xp = reinterpret_cast<const float4*>(x + (size_t)n * SD);
      const float4* mp = reinterpret_cast<const float4*>(msgs + (size_t)n * OC);
      float z1[HID];
#pragma unroll
      for (int j = 0; j < HID; ++j) z1[j] = 0.f;
      mv_acc<8, 0>(xp, w1s, z1);
      mv_acc<4, SD>(mp, w1s, z1);
#pragma unroll
      for (int i = 0; i < HID; ++i) z1[i] = fmaxf(0.f, fmaf(z1[i], sc1[i], sf1[i]));
      mv_reg(z1, w2s, z2);
    }
    tile_accum(z2, tile, h, g, s, q);
  }
  tile_finish(tile, h, g, s, q, stats + 192);
}

__global__ __launch_bounds__(256) void k10_own_out(
    const float* __restrict__ x, const float* __restrict__ msgs,
    const float* __restrict__ w1, const float* __restrict__ w2,
    const float* __restrict__ w3o, const float* __restrict__ b3o,
    const float* __restrict__ g1, const float* __restrict__ be1,
    const float* __restrict__ g2, const float* __restrict__ be2,
    const float* __restrict__ stats, float* __restrict__ out) {
  __shared__ float w1s[(SD + OC) * HID], w2s[HID * HID], w3s[HID * SD];
  __shared__ float sc1[HID], sf1[HID], sc2[HID], sf2[HID];
  for (int f = threadIdx.x; f < (SD + OC) * HID; f += 256) w1s[f] = w1[f];
  for (int f = threadIdx.x; f < HID * HID; f += 256) w2s[f] = w2[f];
  for (int f = threadIdx.x; f < HID * SD; f += 256) w3s[f] = w3o[f];
  bn_params(stats, 128, 1.f / N_NODES, g1, be1, sc1, sf1);
  bn_params(stats, 192, 1.f / N_NODES, g2, be2, sc2, sf2);
  __syncthreads();
  int n = blockIdx.x * 256 + threadIdx.x;
  if (n >= N_NODES) return;
  const float4* xp = reinterpret_cast<const float4*>(x + (size_t)n * SD);
  const float4* mp = reinterpret_cast<const float4*>(msgs + (size_t)n * OC);
  float z1[HID];
#pragma unroll
  for (int j = 0; j < HID; ++j) z1[j] = 0.f;
  mv_acc<8, 0>(xp, w1s, z1);
  mv_acc<4, SD>(mp, w1s, z1);
#pragma unroll
  for (int i = 0; i < HID; ++i) z1[i] = fmaxf(0.f, fmaf(z1[i], sc1[i], sf1[i]));
  float z2[HID];
  mv_reg(z1, w2s, z2);
#pragma unroll
  for (int i = 0; i < HID; ++i) z2[i] = fmaxf(0.f, fmaf(z2[i], sc2[i], sf2[i]));
  float z3[HID];
  mv_reg(z2, w3s, z3);
  float4* op = reinterpret_cast<float4*>(out + (size_t)n * SD);
#pragma unroll
  for (int j4 = 0; j4 < 8; ++j4) {
    op[j4] = make_float4(z3[j4 * 4 + 0] + b3o[j4 * 4 + 0],
                         z3[j4 * 4 + 1] + b3o[j4 * 4 + 1],
                         z3[j4 * 4 + 2] + b3o[j4 * 4 + 2],
                         z3[j4 * 4 + 3] + b3o[j4 * 4 + 3]);
  }
}

extern "C" void kernel_launch(void* const* d_in, const int* in_sizes, int n_in,
                              void* d_out, int out_size, void* d_ws, size_t ws_size,
                              hipStream_t stream) {
  const float* x    = (const float*)d_in[0];
  const float* ea   = (const float*)d_in[1];
  const int*   ei   = (const int*)d_in[2];
  const float* mw1  = (const float*)d_in[3];
  const float* mg1  = (const float*)d_in[5];
  const float* mbe1 = (const float*)d_in[6];
  const float* mw2  = (const float*)d_in[7];
  const float* mg2  = (const float*)d_in[9];
  const float* mbe2 = (const float*)d_in[10];
  const float* mw3  = (const float*)d_in[11];
  const float* mb3  = (const float*)d_in[12];
  const float* rw   = (const float*)d_in[13];
  const float* rb   = (const float*)d_in[14];
  const float* ow1  = (const float*)d_in[15];
  const float* og1  = (const float*)d_in[17];
  const float* obe1 = (const float*)d_in[18];
  const float* ow2  = (const float*)d_in[19];
  const float* og2  = (const float*)d_in[21];
  const float* obe2 = (const float*)d_in[22];
  const float* ow3  = (const float*)d_in[23];
  const float* ob3  = (const float*)d_in[24];
  float* out = (float*)d_out;

  char* ws = (char*)d_ws;
  float* stats    = (float*)(ws + OFF_STATS);
  int* degS       = (int*)(ws + OFF_DEGS);
  int* curS       = (int*)(ws + OFF_CURS);
  int* degD       = (int*)(ws + OFF_DEGD);
  int* curD       = (int*)(ws + OFF_CURD);
  int* baseS      = (int*)(ws + OFF_BASES);
  int* baseD      = (int*)(ws + OFF_BASED);
  int* posS       = (int*)(ws + OFF_POSS);
  unsigned* combo = (unsigned*)(ws + OFF_COMBO);
  float* agg      = (float*)(ws + OFF_AGG);
  __half* h2s     = (__half*)(ws + OFF_H2S);
  __half* msgb    = (__half*)(ws + OFF_MSGB);

  hipMemsetAsync(ws, 0, 805376, stream);

  kH<<<3125, 256, 0, stream>>>(ei, degS, degD);
  kScan<<<2, 1024, 0, stream>>>(degS, baseS, degD, baseD);
  kRank<<<3125, 256, 0, stream>>>(ei, baseS, baseD, curS, curD, posS, combo);
  sE<0><<<1024, 256, 0, stream>>>(ea, posS, mw1, mw2, mg1, mbe1, stats, h2s);
  sE<1><<<1024, 256, 0, stream>>>(ea, posS, mw1, mw2, mg1, mbe1, stats, h2s);
  k5_gemm<<<3125, 256, 0, stream>>>(x, mw3, mb3, combo, baseS, h2s,
                                    stats, mg2, mbe2, msgb);
  k6_aggr_own<<<3125, 256, 0, stream>>>(baseD, msgb, x, rw, rb, ow1, agg, stats);
  s2_own<<<NTILES, 256, 0, stream>>>(x, agg, ow1, ow2, og1, obe1, stats);
  k10_own_out<<<(N_NODES + 255) / 256, 256, 0, stream>>>(
      x, agg, ow1, ow2, ow3, ob3, og1, obe1, og2, obe2, stats, out);
}

// Round 7
// 711.941 us; speedup vs baseline: 1.1993x; 1.0296x over previous
//
#include <hip/hip_runtime.h>
#include <hip/hip_fp16.h>

// NNConv particle GNN, round 7:
//  - sE<0> (full 102MB ea pass for BN1 stats) DELETED: BN1 stats via exact
//    closed form (round-4-proven): sum_h = easum.w1[:,h], sumsq_h = w1^T M w1,
//    M = ea^T ea computed by MFMA Gram (A-frag == B-frag register contents),
//    split-fp16: M ~= H^T H + H^T L + (H^T L)^T  (P,Q accs, symmetrized at reduce)
//  - kPre fuses posS/combo composition with the M/easum pass (one ea read)
//  - histogram fused into rank kernel (kH deleted; atomics 6.4M -> 3.2M)
//  - kBN1 inlined into sE1 prologue (per-block recompute, ~2us total)
//  - dispatches 10 -> 9
// BN training mode => linear biases b1/b2/own_b1/own_b2 cancel exactly.

#define N_NODES 50000
#define N_EDGES 800000
#define SD 32
#define OC 16
#define HID 32
#define BN_EPS 1e-5f
#define NTILES 196    // ceil(50000/256)

// ---- workspace byte offsets (64B-aligned), total 90,409,856 B ----
#define OFF_STATS   0u          // 256 f (slot1 @64: BN2-edge; @128 own-L1; @192 own-L2)
#define OFF_MA      1024u       // 1024 f  (P+Q accumulation)
#define OFF_MB      5120u       // 1024 f  (Q accumulation)
#define OFF_EASUM   9216u       // 32 f
#define OFF_CURS    9728u       // 50000 i (becomes degS after kR1)
#define OFF_CURD    209728u     // 50000 i   [memset 0..409728)
#define OFF_BASES   409728u     // 50001 i -> pad 609792
#define OFF_BASED   609792u     // 50001 i -> pad 809856
#define OFF_RANKS   809856u     // 800000 i
#define OFF_RKD_POS 4009856u    // 800000 i: rankD, overwritten as posS in kPre
#define OFF_COMBO   7209856u    // 800000 u
#define OFF_AGG     10409856u   // 800000 f
#define OFF_H2S     13609856u   // 25.6M half
#define OFF_MSGB    64809856u   // 12.8M half

typedef _Float16 f16x8 __attribute__((ext_vector_type(8)));
typedef float f32x16 __attribute__((ext_vector_type(16)));

__device__ __forceinline__ float f4get(const float4& v, int ii) {
  return ii == 0 ? v.x : ii == 1 ? v.y : ii == 2 ? v.z : v.w;
}

__device__ __forceinline__ unsigned pack2(float a, float b) {
  __half2 h = __floats2half2_rn(a, b);
  return *reinterpret_cast<unsigned*>(&h);
}
__device__ __forceinline__ void unpk8(uint4 u, float* o) {
  __half2 a = *reinterpret_cast<__half2*>(&u.x), b = *reinterpret_cast<__half2*>(&u.y);
  __half2 c = *reinterpret_cast<__half2*>(&u.z), d = *reinterpret_cast<__half2*>(&u.w);
  float2 fa = __half22float2(a), fb = __half22float2(b);
  float2 fc = __half22float2(c), fd = __half22float2(d);
  o[0] = fa.x; o[1] = fa.y; o[2] = fb.x; o[3] = fb.y;
  o[4] = fc.x; o[5] = fc.y; o[6] = fd.x; o[7] = fd.y;
}

template<int I4, int IOFF>
__device__ __forceinline__ void mv_acc(const float4* __restrict__ rp,
                                       const float* __restrict__ wlds,
                                       float z[HID]) {
#pragma unroll
  for (int i4 = 0; i4 < I4; ++i4) {
    float4 rv = rp[i4];
#pragma unroll
    for (int ii = 0; ii < 4; ++ii) {
      float s = f4get(rv, ii);
      const float* wrow = wlds + (IOFF + i4 * 4 + ii) * HID;
#pragma unroll
      for (int h4 = 0; h4 < HID / 4; ++h4) {
        float4 wv = *reinterpret_cast<const float4*>(wrow + h4 * 4);
        z[h4 * 4 + 0] = fmaf(s, wv.x, z[h4 * 4 + 0]);
        z[h4 * 4 + 1] = fmaf(s, wv.y, z[h4 * 4 + 1]);
        z[h4 * 4 + 2] = fmaf(s, wv.z, z[h4 * 4 + 2]);
        z[h4 * 4 + 3] = fmaf(s, wv.w, z[h4 * 4 + 3]);
      }
    }
  }
}

__device__ __forceinline__ void mv_reg(const float* __restrict__ v,
                                       const float* __restrict__ wlds,
                                       float z[HID]) {
#pragma unroll
  for (int h = 0; h < HID; ++h) z[h] = 0.f;
#pragma unroll
  for (int i = 0; i < HID; ++i) {
    float s = v[i];
    const float* wrow = wlds + i * HID;
#pragma unroll
    for (int h4 = 0; h4 < HID / 4; ++h4) {
      float4 wv = *reinterpret_cast<const float4*>(wrow + h4 * 4);
      z[h4 * 4 + 0] = fmaf(s, wv.x, z[h4 * 4 + 0]);
      z[h4 * 4 + 1] = fmaf(s, wv.y, z[h4 * 4 + 1]);
      z[h4 * 4 + 2] = fmaf(s, wv.z, z[h4 * 4 + 2]);
      z[h4 * 4 + 3] = fmaf(s, wv.w, z[h4 * 4 + 3]);
    }
  }
}

__device__ __forceinline__ void bn_params(const float* __restrict__ stats, int off,
                                          float cntInv, const float* __restrict__ g,
                                          const float* __restrict__ be,
                                          float* __restrict__ sc, float* __restrict__ sf) {
  if (threadIdx.x < HID) {
    int h = threadIdx.x;
    float mean = stats[off + h] * cntInv;
    float var = stats[off + HID + h] * cntInv - mean * mean;
    float s = g[h] * rsqrtf(var + BN_EPS);
    sc[h] = s;
    sf[h] = fmaf(-mean, s, be[h]);
  }
}

__device__ __forceinline__ void tile_accum(const float z[HID], float* __restrict__ tile,
                                           int h, int g, float& s, float& q) {
  int tid = threadIdx.x;
  __syncthreads();
#pragma unroll
  for (int j = 0; j < HID; ++j) tile[tid * 33 + j] = z[j];
  __syncthreads();
#pragma unroll
  for (int k = 0; k < 32; ++k) {
    float v = tile[(g * 32 + k) * 33 + h];
    s += v;
    q = fmaf(v, v, q);
  }
}

__device__ __forceinline__ void tile_finish(float* __restrict__ tile, int h, int g,
                                            float s, float q,
                                            float* __restrict__ gstats) {
  int tid = threadIdx.x;
  __syncthreads();
  tile[g * 32 + h] = s;
  tile[256 + g * 32 + h] = q;
  __syncthreads();
  if (tid < 64) {
    int hh = tid & 31;
    int base = (tid < 32) ? 0 : 256;
    float acc = 0.f;
#pragma unroll
    for (int g2 = 0; g2 < 8; ++g2) acc += tile[base + g2 * 32 + hh];
    atomicAdd(gstats + ((tid < 32) ? hh : (HID + hh)), acc);
  }
}

// ---------------------------------------------------------------------------
// kR1: rank-returning atomics (histogram is the side effect; kH deleted)
__global__ __launch_bounds__(256) void kR1(const int* __restrict__ ei,
                                           int* __restrict__ curS, int* __restrict__ curD,
                                           int* __restrict__ rankS, int* __restrict__ rankD) {
  int e = blockIdx.x * 256 + threadIdx.x;
  int s = ei[e], d = ei[N_EDGES + e];
  rankS[e] = atomicAdd(curS + s, 1);
  rankD[e] = atomicAdd(curD + d, 1);
}

__global__ __launch_bounds__(1024) void kScan(const int* __restrict__ degS, int* __restrict__ baseS,
                                              const int* __restrict__ degD, int* __restrict__ baseD) {
  __shared__ int sc[1024];
  const int* deg = (blockIdx.x == 0) ? degS : degD;
  int* base = (blockIdx.x == 0) ? baseS : baseD;
  int t = threadIdx.x;
  const int C = 49;
  int st = t * C;
  int sum = 0;
  for (int k = 0; k < C; ++k) {
    int i = st + k;
    if (i < N_NODES) sum += deg[i];
  }
  sc[t] = sum;
  __syncthreads();
  for (int s = 1; s < 1024; s <<= 1) {
    int v = (t >= s) ? sc[t - s] : 0;
    __syncthreads();
    sc[t] += v;
    __syncthreads();
  }
  int run = sc[t] - sum;
  for (int k = 0; k < C; ++k) {
    int i = st + k;
    if (i < N_NODES) { base[i] = run; run += deg[i]; }
  }
  if (t == 1023) base[N_NODES] = run;
}

// ---------------------------------------------------------------------------
// kPre: fused (a) posS/combo composition and (b) MFMA Gram M = ea^T ea + easum.
// Gram trick: for X^T X the A-frag and B-frag have IDENTICAL register
// contents (lane l, slot j holds X[edge 8*(l>>5)+j][feat l&31]).
// Split fp16: P += H^T H, Q += H^T L;  M = P + Q + Q^T (L^T L term ~2^-44, dropped).
// NOTE: rankD_posS is read (rankD) then overwritten (posS) at the SAME index by
// the same thread -- intentionally NOT __restrict__.
__global__ __launch_bounds__(256) void kPre(
    const float* __restrict__ ea, const int* __restrict__ ei,
    const int* __restrict__ baseS, const int* __restrict__ baseD,
    const int* __restrict__ rankS, int* rankD_posS, unsigned* __restrict__ combo,
    float* __restrict__ MA, float* __restrict__ MB, float* __restrict__ easum) {
  __shared__ float stg[4][64 * 36];
  __shared__ float red[4][1024];
  __shared__ float esred[4][64];
  int tid = threadIdx.x, lane = tid & 63, wid = tid >> 6;
  int lr = lane & 31, lh = lane >> 5;
  f32x16 P = {}, Q = {};
  float escol = 0.f;
  for (int t = blockIdx.x; t < N_EDGES / 256; t += gridDim.x) {
    int e = t * 256 + tid;
    {  // compose posS + combo
      int s = ei[e], d = ei[N_EDGES + e];
      int ps = baseS[s] + rankS[e];
      int rd = rankD_posS[e];                 // read rankD
      unsigned cb = (unsigned)(baseD[d] + rd) | ((unsigned)(s & 15) << 27);
      rankD_posS[e] = ps;                     // overwrite as posS (same thread/index)
      combo[ps] = cb;
    }
    {  // Gram: this wave's 64 edges
      int eb = t * 256 + 64 * wid;
      const float4* rp = reinterpret_cast<const float4*>(ea + (size_t)(eb + lane) * SD);
      float* sp = stg[wid] + lane * 36;
#pragma unroll
      for (int u = 0; u < 8; ++u) *reinterpret_cast<float4*>(sp + u * 4) = rp[u];
      __builtin_amdgcn_sched_barrier(0);
      asm volatile("s_waitcnt lgkmcnt(0)" ::: "memory");
      __builtin_amdgcn_sched_barrier(0);
      // easum: lane sums column lr over its 32-edge half
#pragma unroll
      for (int rr = 0; rr < 32; ++rr) escol += stg[wid][(32 * lh + rr) * 36 + lr];
      // 4 k-groups of 16 edges
#pragma unroll
      for (int g = 0; g < 4; ++g) {
        f16x8 h, lo;
#pragma unroll
        for (int j = 0; j < 8; ++j) {
          float v = stg[wid][(g * 16 + 8 * lh + j) * 36 + lr];
          _Float16 hi = (_Float16)v;
          h[j] = hi;
          lo[j] = (_Float16)(v - (float)hi);
        }
        P = __builtin_amdgcn_mfma_f32_32x32x16_f16(h, h, P, 0, 0, 0);
        Q = __builtin_amdgcn_mfma_f32_32x32x16_f16(h, lo, Q, 0, 0, 0);
      }
      __builtin_amdgcn_sched_barrier(0);
    }
  }
  // block reduce P,Q,easum -> atomics
  esred[wid][lane] = escol;
#pragma unroll
  for (int r = 0; r < 16; ++r) red[wid][r * 64 + lane] = P[r];
  __syncthreads();
  float psum[4];
#pragma unroll
  for (int u = 0; u < 4; ++u) {
    int sidx = tid * 4 + u;
    psum[u] = red[0][sidx] + red[1][sidx] + red[2][sidx] + red[3][sidx];
  }
  __syncthreads();
#pragma unroll
  for (int r = 0; r < 16; ++r) red[wid][r * 64 + lane] = Q[r];
  __syncthreads();
#pragma unroll
  for (int u = 0; u < 4; ++u) {
    int sidx = tid * 4 + u;
    float qs = red[0][sidx] + red[1][sidx] + red[2][sidx] + red[3][sidx];
    int r = sidx >> 6, l = sidx & 63;
    int row = (r & 3) + 8 * (r >> 2) + 4 * (l >> 5);
    int col = l & 31;
    atomicAdd(MA + row * 32 + col, psum[u] + qs);
    atomicAdd(MB + row * 32 + col, qs);
  }
  if (tid < 32) {
    float a = 0.f;
#pragma unroll
    for (int w = 0; w < 4; ++w) a += esred[w][tid] + esred[w][tid + 32];
    atomicAdd(easum + tid, a);
  }
}

// ---------------------------------------------------------------------------
// sE1: inline closed-form BN1 (M = MA + MB^T), then per 32-edge tile:
// z1 mfma (split), BN1+ReLU, L2 mfma, BN2 stats -> slot 64, h2s[posS]=z2 fp16.
__global__ __launch_bounds__(256) void sE1(
    const float* __restrict__ ea, const int* __restrict__ posS,
    const float* __restrict__ w1, const float* __restrict__ w2,
    const float* __restrict__ g1, const float* __restrict__ be1,
    const float* __restrict__ MA, const float* __restrict__ MB,
    const float* __restrict__ easum,
    float* __restrict__ stats, __half* __restrict__ h2s) {
  __shared__ float MAs[1024], MBs[1024], w1f[1024];
  __shared__ float parts[32 * 33];
  __shared__ float easl[32], sc1s[32], sf1s[32];
  __shared__ _Float16 xpose[4][32 * 40];
  __shared__ float sred[4][2][32];
  int tid = threadIdx.x;
  int lane = tid & 63, wid = tid >> 6;
  int lr = lane & 31, lh = lane >> 5;

  // ---- inline BN1 closed form (round-4-verified) ----
  for (int f = tid; f < 1024; f += 256) {
    MAs[f] = MA[f];
    MBs[f] = MB[f];
    w1f[f] = w1[f];
  }
  if (tid < 32) easl[tid] = easum[tid];
  __syncthreads();
  {
    int h = tid & 31;
#pragma unroll
    for (int rep = 0; rep < 4; ++rep) {
      int i = 8 * rep + (tid >> 5);
      float tacc = 0.f;
#pragma unroll
      for (int j = 0; j < 32; ++j)
        tacc = fmaf(MAs[i * 32 + j] + MBs[j * 32 + i], w1f[j * 32 + h], tacc);
      parts[i * 33 + h] = w1f[i * 32 + h] * tacc;
    }
  }
  __syncthreads();
  if (tid < 32) {
    int h = tid;
    float sq = 0.f, sm = 0.f;
#pragma unroll
    for (int i = 0; i < 32; ++i) {
      sq += parts[i * 33 + h];
      sm = fmaf(easl[i], w1f[i * 32 + h], sm);
    }
    float mean = sm * (1.f / N_EDGES);
    float var = sq * (1.f / N_EDGES) - mean * mean;
    float s = g1[h] * rsqrtf(var + BN_EPS);
    sc1s[h] = s;
    sf1s[h] = fmaf(-mean, s, be1[h]);
  }
  __syncthreads();
  float sc1 = sc1s[lr], sf1 = sf1s[lr];

  // ---- B fragments (VGPR-resident) ----
  f16x8 w1h[2], w1l[2], w2h[2], w2l[2];
#pragma unroll
  for (int kf = 0; kf < 2; ++kf) {
#pragma unroll
    for (int j = 0; j < 8; ++j) {
      int k = kf * 16 + lh * 8 + j;
      float v = w1f[k * HID + lr];
      _Float16 hi = (_Float16)v;
      w1h[kf][j] = hi;
      w1l[kf][j] = (_Float16)(v - (float)hi);
      float u = w2[k * HID + lr];
      _Float16 uh = (_Float16)u;
      w2h[kf][j] = uh;
      w2l[kf][j] = (_Float16)(u - (float)uh);
    }
  }
  float ssum = 0.f, ssq = 0.f;
  _Float16* xp = xpose[wid];

  for (int t = blockIdx.x * 4 + wid; t < N_EDGES / 32; t += gridDim.x * 4) {
    int e0 = t * 32;
    f16x8 ah[2], al[2];
#pragma unroll
    for (int kf = 0; kf < 2; ++kf) {
      const float4* p = reinterpret_cast<const float4*>(
          ea + (size_t)(e0 + lr) * SD + kf * 16 + lh * 8);
      float4 v0 = p[0], v1 = p[1];
      float vv[8] = {v0.x, v0.y, v0.z, v0.w, v1.x, v1.y, v1.z, v1.w};
#pragma unroll
      for (int j = 0; j < 8; ++j) {
        _Float16 hi = (_Float16)vv[j];
        ah[kf][j] = hi;
        al[kf][j] = (_Float16)(vv[j] - (float)hi);
      }
    }
    f32x16 acc = {};
#pragma unroll
    for (int kf = 0; kf < 2; ++kf) {
      acc = __builtin_amdgcn_mfma_f32_32x32x16_f16(ah[kf], w1h[kf], acc, 0, 0, 0);
      acc = __builtin_amdgcn_mfma_f32_32x32x16_f16(al[kf], w1h[kf], acc, 0, 0, 0);
      acc = __builtin_amdgcn_mfma_f32_32x32x16_f16(ah[kf], w1l[kf], acc, 0, 0, 0);
    }
#pragma unroll
    for (int r = 0; r < 16; ++r) {
      int row = (r & 3) + 8 * (r >> 2) + 4 * lh;
      float h1 = fmaxf(0.f, fmaf(acc[r], sc1, sf1));
      xp[row * 40 + lr] = (_Float16)h1;
    }
    __builtin_amdgcn_sched_barrier(0);
    asm volatile("s_waitcnt lgkmcnt(0)" ::: "memory");
    __builtin_amdgcn_sched_barrier(0);
    f32x16 acc2 = {};
#pragma unroll
    for (int kf = 0; kf < 2; ++kf) {
      f16x8 a2 = *reinterpret_cast<const f16x8*>(xp + lr * 40 + kf * 16 + lh * 8);
      acc2 = __builtin_amdgcn_mfma_f32_32x32x16_f16(a2, w2h[kf], acc2, 0, 0, 0);
      acc2 = __builtin_amdgcn_mfma_f32_32x32x16_f16(a2, w2l[kf], acc2, 0, 0, 0);
    }
#pragma unroll
    for (int r = 0; r < 16; ++r) {
      ssum += acc2[r];
      ssq = fmaf(acc2[r], acc2[r], ssq);
    }
    __builtin_amdgcn_sched_barrier(0);
    asm volatile("s_waitcnt lgkmcnt(0)" ::: "memory");
    __builtin_amdgcn_sched_barrier(0);
#pragma unroll
    for (int r = 0; r < 16; ++r) {
      int row = (r & 3) + 8 * (r >> 2) + 4 * lh;
      xp[row * 40 + lr] = (_Float16)acc2[r];
    }
    __builtin_amdgcn_sched_barrier(0);
    asm volatile("s_waitcnt lgkmcnt(0)" ::: "memory");
    __builtin_amdgcn_sched_barrier(0);
    int ps = posS[e0 + lr];
    uint4 va = *reinterpret_cast<const uint4*>(xp + lr * 40 + lh * 16);
    uint4 vb = *reinterpret_cast<const uint4*>(xp + lr * 40 + lh * 16 + 8);
    __half* dst = (__half*)h2s + (size_t)ps * HID + lh * 16;
    *reinterpret_cast<uint4*>(dst) = va;
    *reinterpret_cast<uint4*>(dst + 8) = vb;
    __builtin_amdgcn_sched_barrier(0);
  }
  ssum += __shfl_xor(ssum, 32);
  ssq += __shfl_xor(ssq, 32);
  if (lane < 32) {
    sred[wid][0][lane] = ssum;
    sred[wid][1][lane] = ssq;
  }
  __syncthreads();
  if (tid < 64) {
    int h = tid & 31, part = tid >> 5;
    float a = sred[0][part][h] + sred[1][part][h] + sred[2][part][h] + sred[3][part][h];
    atomicAdd(stats + 64 + part * 32 + h, a);
  }
}

// ---------------------------------------------------------------------------
// K5-GEMM: block owns 16 src nodes; T + xb in LDS; coalesced slot loop;
// msg -> dst-sorted fp16 buffer. (unchanged from round 6)
__global__ __launch_bounds__(256) void k5_gemm(
    const float* __restrict__ x, const float* __restrict__ w3,
    const float* __restrict__ b3, const unsigned* __restrict__ combo,
    const int* __restrict__ baseS, const __half* __restrict__ h2s,
    const float* __restrict__ stats, const float* __restrict__ g2,
    const float* __restrict__ be2, __half* __restrict__ msgb) {
  __shared__ float Tl[16 * 516];
  __shared__ float xsl[16][33];
  __shared__ float xbl[256];
  __shared__ float b3s[SD * OC];
  __shared__ float sc2[HID], sf2[HID];
  __shared__ int jr[2];
  int tid = threadIdx.x;
  int n0 = blockIdx.x * 16;
  for (int f = tid; f < 16 * SD; f += 256)
    xsl[f >> 5][f & 31] = x[(size_t)n0 * SD + f];
  for (int f = tid; f < SD * OC; f += 256) b3s[f] = b3[f];
  if (tid == 0) jr[0] = baseS[n0];
  if (tid == 1) jr[1] = baseS[n0 + 16];
  bn_params(stats, 64, 1.f / N_EDGES, g2, be2, sc2, sf2);
  __syncthreads();
  {
    int nl = tid >> 4, o = tid & 15;
    float a1 = 0.f;
#pragma unroll
    for (int i = 0; i < SD; ++i) a1 = fmaf(xsl[nl][i], b3s[i * OC + o], a1);
    xbl[tid] = a1;
  }
  {
    int oH = tid & 1, hh = (tid >> 1) & 31, ng = tid >> 6;
    float acc[4][8];
#pragma unroll
    for (int k = 0; k < 4; ++k)
#pragma unroll
      for (int j = 0; j < 8; ++j) acc[k][j] = 0.f;
    const float* wbase = w3 + hh * (SD * OC) + oH * 8;
#pragma unroll
    for (int i = 0; i < SD; ++i) {
      float4 wa = *reinterpret_cast<const float4*>(wbase + i * OC);
      float4 wb = *reinterpret_cast<const float4*>(wbase + i * OC + 4);
#pragma unroll
      for (int k = 0; k < 4; ++k) {
        float xv = xsl[ng * 4 + k][i];
        acc[k][0] = fmaf(xv, wa.x, acc[k][0]);
        acc[k][1] = fmaf(xv, wa.y, acc[k][1]);
        acc[k][2] = fmaf(xv, wa.z, acc[k][2]);
        acc[k][3] = fmaf(xv, wa.w, acc[k][3]);
        acc[k][4] = fmaf(xv, wb.x, acc[k][4]);
        acc[k][5] = fmaf(xv, wb.y, acc[k][5]);
        acc[k][6] = fmaf(xv, wb.z, acc[k][6]);
        acc[k][7] = fmaf(xv, wb.w, acc[k][7]);
      }
    }
#pragma unroll
    for (int k = 0; k < 4; ++k)
#pragma unroll
      for (int jj = 0; jj < 8; ++jj)
        Tl[(ng * 4 + k) * 516 + (oH * 8 + jj) * 32 + hh] = acc[k][jj];
  }
  __syncthreads();
  int jbeg = jr[0], jend = jr[1];
  for (int j = jbeg + tid; j < jend; j += 256) {
    unsigned c = combo[j];
    int dp = (int)(c & 0x07FFFFFFu);
    int nl = (int)(c >> 27);
    const uint4* hp = reinterpret_cast<const uint4*>(h2s + (size_t)j * HID);
    uint4 u0 = hp[0], u1 = hp[1], u2 = hp[2], u3 = hp[3];
    float h2v[HID];
    unpk8(u0, h2v + 0); unpk8(u1, h2v + 8);
    unpk8(u2, h2v + 16); unpk8(u3, h2v + 24);
#pragma unroll
    for (int k = 0; k < HID; ++k) h2v[k] = fmaxf(0.f, fmaf(h2v[k], sc2[k], sf2[k]));
    float m[OC];
#pragma unroll
    for (int o = 0; o < OC; ++o) m[o] = xbl[nl * 16 + o];
#pragma unroll
    for (int o = 0; o < OC; ++o) {
      const float* tb = Tl + nl * 516 + o * 32;
      float a = m[o];
#pragma unroll
      for (int h4 = 0; h4 < 8; ++h4) {
        float4 t = *reinterpret_cast<const float4*>(tb + h4 * 4);
        a = fmaf(h2v[h4 * 4 + 0], t.x, a);
        a = fmaf(h2v[h4 * 4 + 1], t.y, a);
        a = fmaf(h2v[h4 * 4 + 2], t.z, a);
        a = fmaf(h2v[h4 * 4 + 3], t.w, a);
      }
      m[o] = a;
    }
    unsigned us[8];
#pragma unroll
    for (int q = 0; q < 8; ++q) us[q] = pack2(m[2 * q], m[2 * q + 1]);
    uint4* mp = reinterpret_cast<uint4*>(msgb + (size_t)dp * OC);
    mp[0] = make_uint4(us[0], us[1], us[2], us[3]);
    mp[1] = make_uint4(us[4], us[5], us[6], us[7]);
  }
}

// ---------------------------------------------------------------------------
// K6: segment-sum + root term -> agg (=messages); fused own-L1 stats (slot 2)
__global__ __launch_bounds__(256) void k6_aggr_own(
    const int* __restrict__ baseD, const __half* __restrict__ msgb,
    const float* __restrict__ x, const float* __restrict__ rootw,
    const float* __restrict__ rootb, const float* __restrict__ ow1,
    float* __restrict__ agg, float* __restrict__ stats) {
  __shared__ float xsl[16][33];
  __shared__ float aggl[16 * 17];
  __shared__ float rws[SD * OC];
  __shared__ float ow1s[(SD + OC) * HID];
  __shared__ float zt[16 * 33];
  __shared__ float rbs[OC];
  int tid = threadIdx.x;
  int n0 = blockIdx.x * 16;
  for (int f = tid; f < 16 * SD; f += 256) xsl[f >> 5][f & 31] = x[(size_t)n0 * SD + f];
  for (int f = tid; f < SD * OC; f += 256) rws[f] = rootw[f];
  for (int f = tid; f < (SD + OC) * HID; f += 256) ow1s[f] = ow1[f];
  if (tid < OC) rbs[tid] = rootb[tid];
  __syncthreads();
  int nl = tid >> 4, o = tid & 15;
  int d = n0 + nl;
  float r = rbs[o];
#pragma unroll
  for (int i = 0; i < SD; ++i) r = fmaf(xsl[nl][i], rws[i * OC + o], r);
  int b0 = baseD[d], b1 = baseD[d + 1];
  float s = 0.f;
  for (int j = b0; j < b1; ++j) s += __half2float(msgb[(size_t)j * OC + o]);
  float val = r + s;
  agg[(size_t)d * OC + o] = val;
  aggl[nl * 17 + o] = val;
  __syncthreads();
  float za = 0.f, zb = 0.f;
#pragma unroll
  for (int i = 0; i < SD; ++i) {
    float xv = xsl[nl][i];
    za = fmaf(xv, ow1s[i * HID + o], za);
    zb = fmaf(xv, ow1s[i * HID + o + 16], zb);
  }
#pragma unroll
  for (int i = 0; i < OC; ++i) {
    float mv = aggl[nl * 17 + i];
    za = fmaf(mv, ow1s[(SD + i) * HID + o], za);
    zb = fmaf(mv, ow1s[(SD + i) * HID + o + 16], zb);
  }
  zt[nl * 33 + o] = za;
  zt[nl * 33 + o + 16] = zb;
  __syncthreads();
  if (tid < 64) {
    int h = tid & 31;
    bool issq = tid >= 32;
    float acc = 0.f;
#pragma unroll
    for (int k = 0; k < 16; ++k) {
      float v = zt[k * 33 + h];
      acc += issq ? v * v : v;
    }
    atomicAdd(stats + 128 + (issq ? 32 : 0) + h, acc);
  }
}

// ---------------------------------------------------------------------------
__global__ __launch_bounds__(256) void s2_own(
    const float* __restrict__ x, const float* __restrict__ msgs,
    const float* __restrict__ w1, const float* __restrict__ w2,
    const float* __restrict__ g1, const float* __restrict__ be1,
    float* __restrict__ stats) {
  __shared__ float w1s[(SD + OC) * HID], w2s[HID * HID];
  __shared__ float sc1[HID], sf1[HID];
  __shared__ float tile[256 * 33];
  for (int f = threadIdx.x; f < (SD + OC) * HID; f += 256) w1s[f] = w1[f];
  for (int f = threadIdx.x; f < HID * HID; f += 256) w2s[f] = w2[f];
  bn_params(stats, 128, 1.f / N_NODES, g1, be1, sc1, sf1);
  int h = threadIdx.x & 31, g = threadIdx.x >> 5;
  float s = 0.f, q = 0.f;
  __syncthreads();
#pragma unroll 1
  for (int t = blockIdx.x; t < NTILES; t += gridDim.x) {
    int n = t * 256 + threadIdx.x;
    float z2[HID];
#pragma unroll
    for (int j = 0; j < HID; ++j) z2[j] = 0.f;
    if (n < N_NODES) {
      const float4* xp = reinterpret_cast<const float4*>(x + (size_t)n * SD);
      const float4* mp = reinterpret_cast<const float4*>(msgs + (size_t)n * OC);
      float z1[HID];
#pragma unroll
      for (int j = 0; j < HID; ++j) z1[j] = 0.f;
      mv_acc<8, 0>(xp, w1s, z1);
      mv_acc<4, SD>(mp, w1s, z1);
#pragma unroll
      for (int i = 0; i < HID; ++i) z1[i] = fmaxf(0.f, fmaf(z1[i], sc1[i], sf1[i]));
      mv_reg(z1, w2s, z2);
    }
    tile_accum(z2, tile, h, g, s, q);
  }
  tile_finish(tile, h, g, s, q, stats + 192);
}

__global__ __launch_bounds__(256) void k10_own_out(
    const float* __restrict__ x, const float* __restrict__ msgs,
    const float* __restrict__ w1, const float* __restrict__ w2,
    const float* __restrict__ w3o, const float* __restrict__ b3o,
    const float* __restrict__ g1, const float* __restrict__ be1,
    const float* __restrict__ g2, const float* __restrict__ be2,
    const float* __restrict__ stats, float* __restrict__ out) {
  __shared__ float w1s[(SD + OC) * HID], w2s[HID * HID], w3s[HID * SD];
  __shared__ float sc1[HID], sf1[HID], sc2[HID], sf2[HID];
  for (int f = threadIdx.x; f < (SD + OC) * HID; f += 256) w1s[f] = w1[f];
  for (int f = threadIdx.x; f < HID * HID; f += 256) w2s[f] = w2[f];
  for (int f = threadIdx.x; f < HID * SD; f += 256) w3s[f] = w3o[f];
  bn_params(stats, 128, 1.f / N_NODES, g1, be1, sc1, sf1);
  bn_params(stats, 192, 1.f / N_NODES, g2, be2, sc2, sf2);
  __syncthreads();
  int n = blockIdx.x * 256 + threadIdx.x;
  if (n >= N_NODES) return;
  const float4* xp = reinterpret_cast<const float4*>(x + (size_t)n * SD);
  const float4* mp = reinterpret_cast<const float4*>(msgs + (size_t)n * OC);
  float z1[HID];
#pragma unroll
  for (int j = 0; j < HID; ++j) z1[j] = 0.f;
  mv_acc<8, 0>(xp, w1s, z1);
  mv_acc<4, SD>(mp, w1s, z1);
#pragma unroll
  for (int i = 0; i < HID; ++i) z1[i] = fmaxf(0.f, fmaf(z1[i], sc1[i], sf1[i]));
  float z2[HID];
  mv_reg(z1, w2s, z2);
#pragma unroll
  for (int i = 0; i < HID; ++i) z2[i] = fmaxf(0.f, fmaf(z2[i], sc2[i], sf2[i]));
  float z3[HID];
  mv_reg(z2, w3s, z3);
  float4* op = reinterpret_cast<float4*>(out + (size_t)n * SD);
#pragma unroll
  for (int j4 = 0; j4 < 8; ++j4) {
    op[j4] = make_float4(z3[j4 * 4 + 0] + b3o[j4 * 4 + 0],
                         z3[j4 * 4 + 1] + b3o[j4 * 4 + 1],
                         z3[j4 * 4 + 2] + b3o[j4 * 4 + 2],
                         z3[j4 * 4 + 3] + b3o[j4 * 4 + 3]);
  }
}

extern "C" void kernel_launch(void* const* d_in, const int* in_sizes, int n_in,
                              void* d_out, int out_size, void* d_ws, size_t ws_size,
                              hipStream_t stream) {
  const float* x    = (const float*)d_in[0];
  const float* ea   = (const float*)d_in[1];
  const int*   ei   = (const int*)d_in[2];
  const float* mw1  = (const float*)d_in[3];
  const float* mg1  = (const float*)d_in[5];
  const float* mbe1 = (const float*)d_in[6];
  const float* mw2  = (const float*)d_in[7];
  const float* mg2  = (const float*)d_in[9];
  const float* mbe2 = (const float*)d_in[10];
  const float* mw3  = (const float*)d_in[11];
  const float* mb3  = (const float*)d_in[12];
  const float* rw   = (const float*)d_in[13];
  const float* rb   = (const float*)d_in[14];
  const float* ow1  = (const float*)d_in[15];
  const float* og1  = (const float*)d_in[17];
  const float* obe1 = (const float*)d_in[18];
  const float* ow2  = (const float*)d_in[19];
  const float* og2  = (const float*)d_in[21];
  const float* obe2 = (const float*)d_in[22];
  const float* ow3  = (const float*)d_in[23];
  const float* ob3  = (const float*)d_in[24];
  float* out = (float*)d_out;

  char* ws = (char*)d_ws;
  float* stats    = (float*)(ws + OFF_STATS);
  float* MA       = (float*)(ws + OFF_MA);
  float* MB       = (float*)(ws + OFF_MB);
  float* easum    = (float*)(ws + OFF_EASUM);
  int* curS       = (int*)(ws + OFF_CURS);
  int* curD       = (int*)(ws + OFF_CURD);
  int* baseS      = (int*)(ws + OFF_BASES);
  int* baseD      = (int*)(ws + OFF_BASED);
  int* rankS      = (int*)(ws + OFF_RANKS);
  int* rankD_posS = (int*)(ws + OFF_RKD_POS);
  unsigned* combo = (unsigned*)(ws + OFF_COMBO);
  float* agg      = (float*)(ws + OFF_AGG);
  __half* h2s     = (__half*)(ws + OFF_H2S);
  __half* msgb    = (__half*)(ws + OFF_MSGB);

  // zero: stats, MA, MB, easum, curS, curD
  hipMemsetAsync(ws, 0, 409728, stream);

  kR1<<<3125, 256, 0, stream>>>(ei, curS, curD, rankS, rankD_posS);
  kScan<<<2, 1024, 0, stream>>>(curS, baseS, curD, baseD);
  kPre<<<512, 256, 0, stream>>>(ea, ei, baseS, baseD, rankS, rankD_posS, combo,
                                MA, MB, easum);
  sE1<<<1024, 256, 0, stream>>>(ea, rankD_posS, mw1, mw2, mg1, mbe1,
                                MA, MB, easum, stats, h2s);
  k5_gemm<<<3125, 256, 0, stream>>>(x, mw3, mb3, combo, baseS, h2s,
                                    stats, mg2, mbe2, msgb);
  k6_aggr_own<<<3125, 256, 0, stream>>>(baseD, msgb, x, rw, rb, ow1, agg, stats);
  s2_own<<<NTILES, 256, 0, stream>>>(x, agg, ow1, ow2, og1, obe1, stats);
  k10_own_out<<<(N_NODES + 255) / 256, 256, 0, stream>>>(
      x, agg, ow1, ow2, ow3, ob3, og1, obe1, og2, obe2, stats, out);
}